// Round 14
// baseline (1009.869 us; speedup 1.0000x reference)
//
#include <hip/hip_runtime.h>
#include <math.h>

typedef __bf16 bf16_t;
typedef bf16_t bf16x8 __attribute__((ext_vector_type(8)));
typedef bf16_t bf16x4 __attribute__((ext_vector_type(4)));
typedef float f32x4 __attribute__((ext_vector_type(4)));

#define TOKS 73728
#define CCH 192

__device__ __forceinline__ float gelu_f(float x) {
  float x2 = x*x;
  float u = 1.5957691216057308f * x * fmaf(0.044715f, x2, 1.0f);
  float e = __expf(-u);
  return x * __builtin_amdgcn_rcpf(1.0f + e);
}

__device__ __forceinline__ void glds16(const void* g, void* l) {
  __builtin_amdgcn_global_load_lds(
      (const __attribute__((address_space(1))) void*)g,
      (__attribute__((address_space(3))) void*)l, 16, 0, 0);
}

// ---------- fused prep ----------
__global__ void prep_all_k(const float* __restrict__ qw, const float* __restrict__ qs,
                           const float* __restrict__ pw, const float* __restrict__ f1,
                           const float* __restrict__ f2, const float* __restrict__ cw,
                           const float* __restrict__ rpb,
                           bf16_t* __restrict__ WwinT, bf16_t* __restrict__ WstrT,
                           bf16_t* __restrict__ WprojT, bf16_t* __restrict__ Wfc1T,
                           bf16_t* __restrict__ Wfc2T, bf16_t* __restrict__ WconvT,
                           float* __restrict__ RPB2) {
  long idx = (long)blockIdx.x*256 + threadIdx.x;
  auto tr = [](const float* in, bf16_t* out, long i, int K, int N) {
    long kn = (long)K*N;
    long c = i / kn;
    int rem = (int)(i - c*kn);
    int k = rem / N, n = rem % N;
    out[c*kn + (long)n*K + k] = (bf16_t)in[i];
  };
  if (idx < 110592)        tr(qw, WwinT, idx, 96, 288);
  else if (idx < 221184)   tr(qs, WstrT, idx-110592, 96, 288);
  else if (idx < 368640)   tr(pw, WprojT, idx-221184, 192, 192);
  else if (idx < 958464)   tr(f1, Wfc1T, idx-368640, 192, 768);
  else if (idx < 1548288)  tr(f2, Wfc2T, idx-958464, 768, 192);
  else if (idx < 1880064) {
    int i2 = (int)(idx - 1548288);
    int tap = i2 / 36864;
    int co = (i2 / 192) % 192;
    int ci = i2 % 192;
    WconvT[i2] = (bf16_t)cw[(co*192 + ci)*9 + tap];
  } else if (idx < 1945600) {
    int i2 = (int)(idx - 1880064);
    int i = i2 >> 14;
    int rem = i2 & 16383;
    int h = rem >> 12;
    int k = (rem >> 6) & 63;
    int c = (rem >> 2) & 15;
    int nt = rem & 3;
    int q = nt*16 + c;
    int ridx = ((q>>3) - (k>>3) + 7)*15 + ((q&7) - (k&7) + 7);
    RPB2[i2] = rpb[(i*225 + ridx)*4 + h];
  }
}

// ---------- LN0 ----------
__global__ __launch_bounds__(256) void ln0_k(const float* __restrict__ x,
    const float* __restrict__ gg, const float* __restrict__ bb,
    bf16_t* __restrict__ out, float* __restrict__ xcopy) {
  const int wid = blockIdx.x*4 + (threadIdx.x >> 6);
  const int l = threadIdx.x & 63;
  const float* row = x + (long)wid*CCH;
  float v0 = row[l], v1 = row[l+64], v2 = row[l+128];
  float s = v0+v1+v2, s2 = v0*v0+v1*v1+v2*v2;
  #pragma unroll
  for (int off=1; off<64; off<<=1) { s += __shfl_xor(s, off); s2 += __shfl_xor(s2, off); }
  float mu = s * (1.f/CCH);
  float rstd = rsqrtf(s2*(1.f/CCH) - mu*mu + 1e-5f);
  float* crow = xcopy + (long)wid*CCH;
  crow[l] = v0; crow[l+64] = v1; crow[l+128] = v2;
  bf16_t* orow = out + (long)wid*CCH;
  orow[l]     = (bf16_t)((v0-mu)*rstd*gg[l]     + bb[l]);
  orow[l+64]  = (bf16_t)((v1-mu)*rstd*gg[l+64]  + bb[l+64]);
  orow[l+128] = (bf16_t)((v2-mu)*rstd*gg[l+128] + bb[l+128]);
}

// ---------- fused qkv GEMM v2: BM=256, BN=96, BK=32 ----------
__global__ __launch_bounds__(256) void gemmq_k(
    const bf16_t* __restrict__ xn,
    const bf16_t* __restrict__ BtW, const bf16_t* __restrict__ BtS,
    const float* __restrict__ biasW, const float* __restrict__ biasS,
    bf16_t* __restrict__ outb) {
  constexpr int BK=32, MASK=3;
  __shared__ bf16_t As[2][256*32];   // 32KB
  __shared__ bf16_t Bs[2][96*32];    // 12KB
  const int tid = threadIdx.x;
  const int w = tid >> 6, l = tid & 63;
  const int lr = l & 15, lk = l >> 4;
  const int ri = l >> 2, si = l & MASK;
  const long m0 = (long)blockIdx.x * 256;
  const bool iswin = blockIdx.y < 3;
  const int n0 = (iswin ? blockIdx.y : blockIdx.y - 3) * 96;
  const bf16_t* A = iswin ? xn : xn + 96;
  const bf16_t* Bt = iswin ? BtW : BtS;
  const float* bias = iswin ? biasW : biasS;
  const int ooff = iswin ? 0 : 288;

  f32x4 acc[4][6];
  #pragma unroll
  for (int mi=0;mi<4;++mi)
    #pragma unroll
    for (int ni=0;ni<6;++ni) acc[mi][ni] = (f32x4){0.f,0.f,0.f,0.f};

  auto stage = [&](int buf, int k0) {
    #pragma unroll
    for (int j = 0; j < 4; ++j) {
      const int s = j*4 + w;           // 16 A slots
      const int gr = s*16 + ri;
      glds16(A + (m0+gr)*192L + k0 + ((si ^ (gr&MASK))*8), &As[buf][s*512]);
    }
    #pragma unroll
    for (int j = 0; j < 2; ++j) {
      const int s = j*4 + w;
      if (s < 6) {
        const int gr = s*16 + ri;
        glds16(Bt + (long)(n0+gr)*96 + k0 + ((si ^ (gr&MASK))*8), &Bs[buf][s*512]);
      }
    }
  };

  stage(0, 0);
  __syncthreads();
  for (int kt = 0; kt < 3; ++kt) {
    const int cur = kt & 1;
    if (kt + 1 < 3) stage(cur^1, (kt+1)*BK);
    bf16x8 af[4], bfr[6];
    #pragma unroll
    for (int mi=0;mi<4;++mi) {
      const int ar = w*64 + mi*16 + lr;
      const int slot = lk ^ (ar & MASK);
      af[mi] = *(const bf16x8*)(&As[cur][ar*32 + slot*8]);
    }
    #pragma unroll
    for (int ni=0;ni<6;++ni) {
      const int br = ni*16 + lr;
      const int slot = lk ^ (br & MASK);
      bfr[ni] = *(const bf16x8*)(&Bs[cur][br*32 + slot*8]);
    }
    #pragma unroll
    for (int mi=0;mi<4;++mi)
      #pragma unroll
      for (int ni=0;ni<6;++ni)
        acc[mi][ni] = __builtin_amdgcn_mfma_f32_16x16x32_bf16(af[mi], bfr[ni], acc[mi][ni], 0, 0, 0);
    __syncthreads();
  }

  #pragma unroll
  for (int mi=0;mi<4;++mi) {
    const long r0 = m0 + w*64 + mi*16 + lk*4;
    #pragma unroll
    for (int ni=0;ni<6;++ni) {
      const int col = n0 + ni*16 + lr;
      const float bs = bias[col];
      #pragma unroll
      for (int e=0;e<4;++e) {
        const long row = r0 + e;
        outb[row*576 + ooff + col] = (bf16_t)(acc[mi][ni][e] + bs);
      }
    }
  }
}

// ---------- GEMM-B: BM=128, BN=192, BK=64, 512 threads, fused resid+LN ----------
template<int EPI>
__global__ __launch_bounds__(512) void gemmb_k(
    const bf16_t* __restrict__ A,
    const bf16_t* __restrict__ Bt,
    const float* __restrict__ bias,
    float* __restrict__ resid,
    bf16_t* __restrict__ xnout,
    const float* __restrict__ gg, const float* __restrict__ bb,
    int K) {
  constexpr int BK=64, MASK=7;
  __shared__ bf16_t As[2][128*64];
  __shared__ bf16_t Bs[2][192*64];
  const int tid = threadIdx.x;
  const int w = tid >> 6, l = tid & 63;
  const int lr = l & 15, lk = l >> 4;
  const int ri = l >> 3, si = l & 7;
  const int wm = w >> 2, wn = w & 3;
  const long m0 = (long)blockIdx.x * 128;

  f32x4 acc[4][3];
  #pragma unroll
  for (int mi=0;mi<4;++mi)
    #pragma unroll
    for (int ni=0;ni<3;++ni) acc[mi][ni] = (f32x4){0.f,0.f,0.f,0.f};

  const int nk = K / BK;
  auto stage = [&](int buf, int k0) {
    #pragma unroll
    for (int j = 0; j < 2; ++j) {
      const int s = j*8 + w;
      const int gr = s*8 + ri;
      glds16(A + (m0+gr)*(long)K + k0 + ((si ^ (gr&MASK))*8), &As[buf][s*512]);
    }
    #pragma unroll
    for (int j = 0; j < 3; ++j) {
      const int s = j*8 + w;
      const int gr = s*8 + ri;
      glds16(Bt + (long)gr*K + k0 + ((si ^ (gr&MASK))*8), &Bs[buf][s*512]);
    }
  };

  stage(0, 0);
  __syncthreads();
  for (int kt = 0; kt < nk; ++kt) {
    const int cur = kt & 1;
    if (kt + 1 < nk) stage(cur^1, (kt+1)*BK);
    #pragma unroll
    for (int ks = 0; ks < 2; ++ks) {
      bf16x8 af[4], bfr[3];
      #pragma unroll
      for (int mi=0;mi<4;++mi) {
        const int ar = wm*64 + mi*16 + lr;
        const int slot = (ks*4 + lk) ^ (ar & MASK);
        af[mi] = *(const bf16x8*)(&As[cur][ar*64 + slot*8]);
      }
      #pragma unroll
      for (int ni=0;ni<3;++ni) {
        const int br = wn*48 + ni*16 + lr;
        const int slot = (ks*4 + lk) ^ (br & MASK);
        bfr[ni] = *(const bf16x8*)(&Bs[cur][br*64 + slot*8]);
      }
      #pragma unroll
      for (int mi=0;mi<4;++mi)
        #pragma unroll
        for (int ni=0;ni<3;++ni)
          acc[mi][ni] = __builtin_amdgcn_mfma_f32_16x16x32_bf16(af[mi], bfr[ni], acc[mi][ni], 0, 0, 0);
    }
    __syncthreads();
  }

  #pragma unroll
  for (int mi=0;mi<4;++mi) {
    #pragma unroll
    for (int ni=0;ni<3;++ni) {
      const int col = wn*48 + ni*16 + lr;
      const float bs = bias[col];
      #pragma unroll
      for (int e=0;e<4;++e) {
        const long row = m0 + wm*64 + mi*16 + lk*4 + e;
        float v = acc[mi][ni][e] + bs + resid[row*CCH + col];
        acc[mi][ni][e] = v;
        resid[row*CCH + col] = v;
        if (EPI == 1) xnout[row*CCH + col] = (bf16_t)v;
      }
    }
  }
  if (EPI == 0) {
    float* red  = (float*)&As[0][0];
    float* stat = red + 1024;
    #pragma unroll
    for (int mi=0;mi<4;++mi) {
      #pragma unroll
      for (int e=0;e<4;++e) {
        float p1 = acc[mi][0][e] + acc[mi][1][e] + acc[mi][2][e];
        float p2 = acc[mi][0][e]*acc[mi][0][e] + acc[mi][1][e]*acc[mi][1][e]
                 + acc[mi][2][e]*acc[mi][2][e];
        #pragma unroll
        for (int off=1; off<16; off<<=1) {
          p1 += __shfl_xor(p1, off);
          p2 += __shfl_xor(p2, off);
        }
        if (lr == 0) {
          const int r = wm*64 + mi*16 + lk*4 + e;
          red[(r*4 + wn)*2]     = p1;
          red[(r*4 + wn)*2 + 1] = p2;
        }
      }
    }
    __syncthreads();
    if (tid < 128) {
      const int r = tid;
      float s1 = red[(r*4+0)*2] + red[(r*4+1)*2] + red[(r*4+2)*2] + red[(r*4+3)*2];
      float s2 = red[(r*4+0)*2+1] + red[(r*4+1)*2+1] + red[(r*4+2)*2+1] + red[(r*4+3)*2+1];
      const float mu = s1 * (1.f/CCH);
      stat[r*2]   = mu;
      stat[r*2+1] = rsqrtf(s2*(1.f/CCH) - mu*mu + 1e-5f);
    }
    __syncthreads();
    #pragma unroll
    for (int mi=0;mi<4;++mi) {
      #pragma unroll
      for (int e=0;e<4;++e) {
        const int r = wm*64 + mi*16 + lk*4 + e;
        const float mu = stat[r*2], rstd = stat[r*2+1];
        #pragma unroll
        for (int ni=0;ni<3;++ni) {
          const int col = wn*48 + ni*16 + lr;
          xnout[(m0+r)*CCH + col] = (bf16_t)((acc[mi][ni][e]-mu)*rstd*gg[col] + bb[col]);
        }
      }
    }
  }
}

// ---------- fc1 GEMM: BM=128, BN=192 (of N=768), BK=64, 512 thr, gelu ----------
__global__ __launch_bounds__(512) void gemmf_k(
    const bf16_t* __restrict__ A,
    const bf16_t* __restrict__ Bt,
    const float* __restrict__ bias,
    bf16_t* __restrict__ outb) {
  constexpr int BK=64, MASK=7;
  __shared__ bf16_t As[2][128*64];
  __shared__ bf16_t Bs[2][192*64];
  const int tid = threadIdx.x;
  const int w = tid >> 6, l = tid & 63;
  const int lr = l & 15, lk = l >> 4;
  const int ri = l >> 3, si = l & 7;
  const int wm = w >> 2, wn = w & 3;
  const long m0 = (long)blockIdx.x * 128;
  const int n0 = blockIdx.y * 192;

  f32x4 acc[4][3];
  #pragma unroll
  for (int mi=0;mi<4;++mi)
    #pragma unroll
    for (int ni=0;ni<3;++ni) acc[mi][ni] = (f32x4){0.f,0.f,0.f,0.f};

  auto stage = [&](int buf, int k0) {
    #pragma unroll
    for (int j = 0; j < 2; ++j) {
      const int s = j*8 + w;
      const int gr = s*8 + ri;
      glds16(A + (m0+gr)*192L + k0 + ((si ^ (gr&MASK))*8), &As[buf][s*512]);
    }
    #pragma unroll
    for (int j = 0; j < 3; ++j) {
      const int s = j*8 + w;
      const int gr = s*8 + ri;
      glds16(Bt + (long)(n0+gr)*192 + k0 + ((si ^ (gr&MASK))*8), &Bs[buf][s*512]);
    }
  };

  stage(0, 0);
  __syncthreads();
  for (int kt = 0; kt < 3; ++kt) {
    const int cur = kt & 1;
    if (kt + 1 < 3) stage(cur^1, (kt+1)*BK);
    #pragma unroll
    for (int ks = 0; ks < 2; ++ks) {
      bf16x8 af[4], bfr[3];
      #pragma unroll
      for (int mi=0;mi<4;++mi) {
        const int ar = wm*64 + mi*16 + lr;
        const int slot = (ks*4 + lk) ^ (ar & MASK);
        af[mi] = *(const bf16x8*)(&As[cur][ar*64 + slot*8]);
      }
      #pragma unroll
      for (int ni=0;ni<3;++ni) {
        const int br = wn*48 + ni*16 + lr;
        const int slot = (ks*4 + lk) ^ (br & MASK);
        bfr[ni] = *(const bf16x8*)(&Bs[cur][br*64 + slot*8]);
      }
      #pragma unroll
      for (int mi=0;mi<4;++mi)
        #pragma unroll
        for (int ni=0;ni<3;++ni)
          acc[mi][ni] = __builtin_amdgcn_mfma_f32_16x16x32_bf16(af[mi], bfr[ni], acc[mi][ni], 0, 0, 0);
    }
    __syncthreads();
  }

  #pragma unroll
  for (int mi=0;mi<4;++mi) {
    #pragma unroll
    for (int ni=0;ni<3;++ni) {
      const int col = n0 + wn*48 + ni*16 + lr;
      const float bs = bias[col];
      #pragma unroll
      for (int e=0;e<4;++e) {
        const long row = m0 + wm*64 + mi*16 + lk*4 + e;
        outb[row*768 + col] = (bf16_t)gelu_f(acc[mi][ni][e] + bs);
      }
    }
  }
}

// ---------- fused attention: blocks <1152 window (MFMA), >=1152 stripe (MFMA) ----------
__global__ __launch_bounds__(256) void attn_k(
    const bf16_t* __restrict__ qkv, const bf16_t* __restrict__ xn,
    bf16_t* __restrict__ aout,
    const float* __restrict__ rpb2, int shift) {
  __shared__ __attribute__((aligned(16))) char smem[50176];
  const int h = threadIdx.x >> 6, l = threadIdx.x & 63;
  const int c = l & 15, g = l >> 4;
  const float scale = 0.20412414523193154f;

  if (blockIdx.x < 1152) {
    bf16_t (*Vs)[64][28] = (bf16_t(*)[64][28])smem;
    bf16_t (*Pl)[64][68] = (bf16_t(*)[64][68])(smem + 14336);
    float  (*invl)[64]   = (float(*)[64])(smem + 49152);
    const int wblk = blockIdx.x;
    const int b = wblk / 576, wi = wblk % 576;
    const int wh = wi / 24, ww = wi % 24;

    auto gtok = [&](int t) -> long {
      int ho = wh*8 + (t>>3) + shift; if (ho >= 192) ho -= 192;
      int wo = ww*8 + (t&7) + shift;  if (wo >= 192) wo -= 192;
      return (long)b*36864 + (long)ho*192 + wo;
    };

    {
      const bf16_t* vsrc = qkv + gtok(l)*576 + 192 + h*24;
      #pragma unroll
      for (int j=0;j<3;++j) {
        *(bf16x4*)(&Vs[h][l][j*8])   = *(const bf16x4*)(vsrc + j*8);
        *(bf16x4*)(&Vs[h][l][j*8+4]) = *(const bf16x4*)(vsrc + j*8 + 4);
      }
      *(bf16x4*)(&Vs[h][l][24]) = (bf16x4){};
    }

    bf16x8 kf[4], qf[4];
    #pragma unroll
    for (int t=0;t<4;++t) {
      bf16x8 z = {};
      kf[t] = z; qf[t] = z;
      if (g < 3) {
        const bf16_t* pb = qkv + gtok(16*t + c)*576 + h*24 + g*8;
        qf[t] = *(const bf16x8*)(pb);
        kf[t] = *(const bf16x8*)(pb + 96);
      }
    }

    f32x4 st[4][4];
    #pragma unroll
    for (int mt=0;mt<4;++mt)
      #pragma unroll
      for (int nt=0;nt<4;++nt)
        st[mt][nt] = __builtin_amdgcn_mfma_f32_16x16x32_bf16(kf[mt], qf[nt], (f32x4){0.f,0.f,0.f,0.f}, 0, 0, 0);

    const float4* rp = (const float4*)rpb2 + (h*64*16 + c);
    #pragma unroll
    for (int mt=0;mt<4;++mt) {
      #pragma unroll
      for (int r=0;r<4;++r) {
        const int k = 16*mt + 4*g + r;
        float4 b4 = rp[k*16];
        st[mt][0][r] = fmaf(st[mt][0][r], scale, b4.x);
        st[mt][1][r] = fmaf(st[mt][1][r], scale, b4.y);
        st[mt][2][r] = fmaf(st[mt][2][r], scale, b4.z);
        st[mt][3][r] = fmaf(st[mt][3][r], scale, b4.w);
      }
    }

    if (shift && (wh==23 || ww==23)) {
      #pragma unroll
      for (int mt=0;mt<4;++mt)
        #pragma unroll
        for (int r=0;r<4;++r) {
          const int kk = 16*mt + 4*g + r;
          const int krc = (wh==23) ? (((kk>>3)<4)?1:2) : 0;
          const int kcc = (ww==23) ? (((kk&7)<4)?1:2) : 0;
          const int kcls = krc*3 + kcc;
          #pragma unroll
          for (int nt=0;nt<4;++nt) {
            const int qq = 16*nt + c;
            const int qrc = (wh==23) ? (((qq>>3)<4)?1:2) : 0;
            const int qcc = (ww==23) ? (((qq&7)<4)?1:2) : 0;
            if (qrc*3 + qcc != kcls) st[mt][nt][r] -= 100.f;
          }
        }
    }

    #pragma unroll
    for (int nt=0;nt<4;++nt) {
      float m = st[0][nt][0];
      #pragma unroll
      for (int mt=0;mt<4;++mt)
        #pragma unroll
        for (int r=0;r<4;++r) m = fmaxf(m, st[mt][nt][r]);
      m = fmaxf(m, __shfl_xor(m, 16));
      m = fmaxf(m, __shfl_xor(m, 32));
      float s = 0.f;
      #pragma unroll
      for (int mt=0;mt<4;++mt)
        #pragma unroll
        for (int r=0;r<4;++r) {
          float p = __expf(st[mt][nt][r] - m);
          st[mt][nt][r] = p;
          s += p;
        }
      s += __shfl_xor(s, 16);
      s += __shfl_xor(s, 32);
      if (g == 0) invl[h][16*nt + c] = 1.f / s;
    }

    #pragma unroll
    for (int mt=0;mt<4;++mt) {
      #pragma unroll
      for (int nt=0;nt<4;++nt) {
        const int q = 16*nt + c;
        const int sl = (4*mt + g) ^ ((q&7)<<1);
        bf16x4 pk;
        #pragma unroll
        for (int r=0;r<4;++r) pk[r] = (bf16_t)st[mt][nt][r];
        *(bf16x4*)(&Pl[h][q][sl*4]) = pk;
      }
    }

    f32x4 oa[4][2];
    #pragma unroll
    for (int mt=0;mt<4;++mt)
      #pragma unroll
      for (int nt=0;nt<2;++nt) oa[mt][nt] = (f32x4){0.f,0.f,0.f,0.f};

    #pragma unroll
    for (int s2=0;s2<2;++s2) {
      bf16x8 pfr[4];
      #pragma unroll
      for (int mt=0;mt<4;++mt) {
        const int q = 16*mt + c;
        const int S0 = (8*s2 + 2*g) ^ ((q&7)<<1);
        bf16x4 lo = *(const bf16x4*)(&Pl[h][q][S0*4]);
        bf16x4 hi = *(const bf16x4*)(&Pl[h][q][S0*4 + 4]);
        #pragma unroll
        for (int r=0;r<4;++r) { pfr[mt][r] = lo[r]; pfr[mt][4+r] = hi[r]; }
      }
      #pragma unroll
      for (int nt=0;nt<2;++nt) {
        const int d = 16*nt + c;
        const int deff = (d < 24) ? d : 24;
        bf16x8 vf;
        #pragma unroll
        for (int e=0;e<8;++e) vf[e] = Vs[h][32*s2 + 8*g + e][deff];
        #pragma unroll
        for (int mt=0;mt<4;++mt)
          oa[mt][nt] = __builtin_amdgcn_mfma_f32_16x16x32_bf16(pfr[mt], vf, oa[mt][nt], 0, 0, 0);
      }
    }

    #pragma unroll
    for (int mt=0;mt<4;++mt) {
      #pragma unroll
      for (int r=0;r<4;++r) {
        const int q = 16*mt + 4*g + r;
        const float inv = invl[h][q];
        bf16_t* ob = aout + gtok(q)*192 + h*24;
        #pragma unroll
        for (int nt=0;nt<2;++nt) {
          const int d = 16*nt + c;
          if (d < 24) ob[d] = (bf16_t)(oa[mt][nt][r] * inv);
        }
      }
    }
  } else {
    bf16_t (*Vs)[64][28]  = (bf16_t(*)[64][28])smem;
    bf16_t (*Ans)[16][40] = (bf16_t(*)[16][40])(smem + 14336);
    bf16_t (*a2s)[16][68] = (bf16_t(*)[16][68])(smem + 19456);
    bf16_t (*a1s)[64][24] = (bf16_t(*)[64][24])(smem + 28160);
    bf16_t (*Ts2)[32][28] = (bf16_t(*)[32][28])(smem + 40448);
    const int wblk = blockIdx.x - 1152;
    const int b = wblk / 576, wi = wblk % 576;
    const int wh = wi / 24, ww = wi % 24;
    const long base0 = (long)b*36864 + (long)(wh*8)*192 + ww*8;
    auto gtok = [&](int t) -> long { return base0 + (long)(t>>3)*192 + (t&7); };

    {
      const bf16_t* vsrc = qkv + gtok(l)*576 + 480 + h*24;
      #pragma unroll
      for (int j=0;j<3;++j) {
        *(bf16x4*)(&Vs[h][l][j*8])   = *(const bf16x4*)(vsrc + j*8);
        *(bf16x4*)(&Vs[h][l][j*8+4]) = *(const bf16x4*)(vsrc + j*8 + 4);
      }
      *(bf16x4*)(&Vs[h][l][24]) = (bf16x4){};
    }
    {
      const int m = l >> 2, dq = l & 3;
      const int ar = m >> 2, ac = m & 3;
      const bf16_t* t0 = xn + (base0 + (long)(2*ar)*192 + 2*ac)*192 + 96 + h*24;
      #pragma unroll
      for (int j=0;j<6;++j) {
        const int d = dq*6 + j;
        float ssum = (float)t0[d] + (float)t0[192+d] + (float)t0[36864+d] + (float)t0[37056+d];
        Ans[h][m][d] = (bf16_t)(0.25f*ssum);
      }
    }
    if (l < 16) {
      *(bf16x4*)(&Ans[h][l][24]) = (bf16x4){};
      *(bf16x4*)(&Ans[h][l][28]) = (bf16x4){};
      bf16_t* z = &Ts2[h][16+l][0];
      #pragma unroll
      for (int j=0;j<7;++j) *(bf16x4*)(z + j*4) = (bf16x4){};
      *(bf16x4*)(&Ts2[h][l][24]) = (bf16x4){};
    }

    bf16x8 anf = *(const bf16x8*)(&Ans[h][c][g*8]);

    bf16x8 kf[4], qf[4];
    #pragma unroll
    for (int t=0;t<4;++t) {
      const bf16_t* pb = qkv + gtok(16*t + c)*576 + 288 + h*24 + g*8;
      qf[t] = *(const bf16x8*)(pb);
      kf[t] = *(const bf16x8*)(pb + 96);
    }

    f32x4 st2[4];
    #pragma unroll
    for (int mt=0;mt<4;++mt)
      st2[mt] = __builtin_amdgcn_mfma_f32_16x16x32_bf16(kf[mt], anf, (f32x4){0.f,0.f,0.f,0.f}, 0, 0, 0);

    {
      float m2 = -1e30f;
      #pragma unroll
      for (int mt=0;mt<4;++mt)
        #pragma unroll
        for (int r=0;r<4;++r) { st2[mt][r] *= scale; m2 = fmaxf(m2, st2[mt][r]); }
      m2 = fmaxf(m2, __shfl_xor(m2, 16));
      m2 = fmaxf(m2, __shfl_xor(m2, 32));
      float s = 0.f;
      #pragma unroll
      for (int mt=0;mt<4;++mt)
        #pragma unroll
        for (int r=0;r<4;++r) { float p = __expf(st2[mt][r] - m2); st2[mt][r] = p; s += p; }
      s += __shfl_xor(s, 16);
      s += __shfl_xor(s, 32);
      const float inv = 1.f / s;
      #pragma unroll
      for (int mt=0;mt<4;++mt) {
        const int sl = (4*mt + g) ^ ((c&7)<<1);
        bf16x4 pk;
        #pragma unroll
        for (int r=0;r<4;++r) pk[r] = (bf16_t)(st2[mt][r] * inv);
        *(bf16x4*)(&a2s[h][c][sl*4]) = pk;
      }
    }

    f32x4 ta[2];
    ta[0] = (f32x4){0.f,0.f,0.f,0.f}; ta[1] = (f32x4){0.f,0.f,0.f,0.f};
    #pragma unroll
    for (int kt=0;kt<2;++kt) {
      const int S0 = (8*kt + 2*g) ^ ((c&7)<<1);
      bf16x4 lo = *(const bf16x4*)(&a2s[h][c][S0*4]);
      bf16x4 hi = *(const bf16x4*)(&a2s[h][c][S0*4 + 4]);
      bf16x8 pf;
      #pragma unroll
      for (int r=0;r<4;++r) { pf[r] = lo[r]; pf[4+r] = hi[r]; }
      #pragma unroll
      for (int nt2=0;nt2<2;++nt2) {
        const int d = 16*nt2 + c;
        const int deff = (d < 24) ? d : 24;
        bf16x8 vf;
        #pragma unroll
        for (int e=0;e<8;++e) vf[e] = Vs[h][kt*32 + 8*g + e][deff];
        ta[nt2] = __builtin_amdgcn_mfma_f32_16x16x32_bf16(pf, vf, ta[nt2], 0, 0, 0);
      }
    }
    #pragma unroll
    for (int nt2=0;nt2<2;++nt2) {
      const int d = 16*nt2 + c;
      if (d < 24) {
        #pragma unroll
        for (int r=0;r<4;++r) Ts2[h][4*g + r][d] = (bf16_t)ta[nt2][r];
      }
    }

    f32x4 st1[4];
    #pragma unroll
    for (int nt=0;nt<4;++nt)
      st1[nt] = __builtin_amdgcn_mfma_f32_16x16x32_bf16(anf, qf[nt], (f32x4){0.f,0.f,0.f,0.f}, 0, 0, 0);

    #pragma unroll
    for (int nt=0;nt<4;++nt) {
      float m1 = -1e30f;
      #pragma unroll
      for (int r=0;r<4;++r) { st1[nt][r] *= scale; m1 = fmaxf(m1, st1[nt][r]); }
      m1 = fmaxf(m1, __shfl_xor(m1, 16));
      m1 = fmaxf(m1, __shfl_xor(m1, 32));
      float s = 0.f;
      #pragma unroll
      for (int r=0;r<4;++r) { float p = __expf(st1[nt][r] - m1); st1[nt][r] = p; s += p; }
      s += __shfl_xor(s, 16);
      s += __shfl_xor(s, 32);
      const float inv1 = 1.f / s;
      bf16x4 ak;
      #pragma unroll
      for (int r=0;r<4;++r) ak[r] = (bf16_t)(st1[nt][r] * inv1);
      *(bf16x4*)(&a1s[h][16*nt + c][4*g]) = ak;
    }

    f32x4 oa[4][2];
    #pragma unroll
    for (int mt=0;mt<4;++mt) { oa[mt][0] = (f32x4){0.f,0.f,0.f,0.f}; oa[mt][1] = (f32x4){0.f,0.f,0.f,0.f}; }
    #pragma unroll
    for (int mt=0;mt<4;++mt) {
      bf16x8 af = {};
      if (g < 2) af = *(const bf16x8*)(&a1s[h][16*mt + c][g*8]);
      #pragma unroll
      for (int nt2=0;nt2<2;++nt2) {
        const int d = 16*nt2 + c;
        const int deff = (d < 24) ? d : 24;
        bf16x8 tf;
        #pragma unroll
        for (int e=0;e<8;++e) tf[e] = Ts2[h][8*g + e][deff];
        oa[mt][nt2] = __builtin_amdgcn_mfma_f32_16x16x32_bf16(af, tf, oa[mt][nt2], 0, 0, 0);
      }
    }

    #pragma unroll
    for (int mt=0;mt<4;++mt) {
      #pragma unroll
      for (int r=0;r<4;++r) {
        const int tw = 16*mt + 4*g + r;
        bf16_t* ob = aout + gtok(tw)*192 + 96 + h*24;
        #pragma unroll
        for (int nt2=0;nt2<2;++nt2) {
          const int d = 16*nt2 + c;
          if (d < 24) ob[d] = (bf16_t)(oa[mt][nt2][r]);
        }
      }
    }
  }
}

// ---------- conv v6: 52KB LDS + XOR bank swizzle on Xs/Bs ----------
__global__ __launch_bounds__(256) void conv6_k(
    const bf16_t* __restrict__ xb,
    const bf16_t* __restrict__ Wc,
    const float* __restrict__ cb,
    const float* __restrict__ res0,
    const bf16_t* __restrict__ zb,
    float* __restrict__ out) {
  __shared__ bf16_t Xs[19968];
  __shared__ bf16_t Bs[6144];
  const int tid = threadIdx.x;
  const int w = tid >> 6, l = tid & 63;
  const int lr = l & 15, lk = l >> 4;
  const int rq = l >> 2;
  const int cqx = ((l & 3) ^ (rq & 3)) * 8;   // XOR-swizzled chslot (key=row&3)
  const int bxr = blockIdx.x;
  const int bx = (bxr & 7) * 48 + (bxr >> 3);
  const int bimg = bx / 192, h = bx % 192;
  const int co0 = blockIdx.y * 64;

  f32x4 acc[3][4];
  #pragma unroll
  for (int mi=0; mi<3; ++mi)
    #pragma unroll
    for (int ni=0; ni<4; ++ni) acc[mi][ni] = (f32x4){0.f,0.f,0.f,0.f};

  auto stageB = [&](int dyg, int kc) {
    #pragma unroll
    for (int j = 0; j < 3; ++j) {
      const int s = j*4 + w;
      const int tap = s >> 2, rem = s & 3;
      const int row = rem*16 + rq;
      glds16(Wc + ((long)((dyg*3 + tap)*192 + co0 + row))*192 + kc + cqx, &Bs[s*512]);
    }
  };
  auto compute = [&](int dyg) {
    #pragma unroll
    for (int tap = 0; tap < 3; ++tap) {
      bf16x8 af[3];
      #pragma unroll
      for (int mi=0; mi<3; ++mi) {
        const int tokcol = w*48 + mi*16 + lr + tap;
        af[mi] = *(const bf16x8*)(&Xs[dyg*6656 + tokcol*32 + ((lk ^ (tokcol&3))*8)]);
      }
      #pragma unroll
      for (int ni=0; ni<4; ++ni) {
        const int br = ni*16 + lr;
        bf16x8 bfr = *(const bf16x8*)(&Bs[tap*2048 + br*32 + ((lk ^ (br&3))*8)]);
        #pragma unroll
        for (int mi=0; mi<3; ++mi)
          acc[mi][ni] = __builtin_amdgcn_mfma_f32_16x16x32_bf16(af[mi], bfr, acc[mi][ni], 0, 0, 0);
      }
    }
  };

  for (int kcs = 0; kcs < 6; ++kcs) {
    const int kc = kcs * 32;
    if (kcs) __syncthreads();
    for (int j = 0; j < 10; ++j) {
      int s = j*4 + w;
      if (s < 39) {
        int dy = s / 13, rem = s - dy*13;
        int tokcol = rem*16 + rq;
        int wc = tokcol - 1;
        int hp = h + dy - 1;
        const bf16_t* src = zb + cqx;
        if (hp >= 0 && hp < 192 && wc >= 0 && wc < 192)
          src = xb + ((long)bimg*36864 + (long)hp*192 + wc)*192 + kc + cqx;
        glds16(src, &Xs[s*512]);
      }
    }
    stageB(0, kc);
    __syncthreads();
    compute(0);
    #pragma unroll
    for (int dyg = 1; dyg < 3; ++dyg) {
      __syncthreads();
      stageB(dyg, kc);
      __syncthreads();
      compute(dyg);
    }
  }

  #pragma unroll
  for (int mi=0; mi<3; ++mi) {
    #pragma unroll
    for (int ni=0; ni<4; ++ni) {
      const int col = co0 + ni*16 + lr;
      const float cbv = cb[col];
      #pragma unroll
      for (int e=0; e<4; ++e) {
        const int tl = w*48 + mi*16 + lk*4 + e;
        const long tok = (long)bimg*36864 + (long)h*192 + tl;
        out[tok*192 + col] = acc[mi][ni][e] + cbv + res0[tok*192 + col];
      }
    }
  }
}

extern "C" void kernel_launch(void* const* d_in, const int* in_sizes, int n_in,
                              void* d_out, int out_size, void* d_ws, size_t ws_size,
                              hipStream_t stream) {
  const float* x_in     = (const float*)d_in[0];
  const float* norm1_g  = (const float*)d_in[1];
  const float* norm1_b  = (const float*)d_in[2];
  const float* qkv_w_w  = (const float*)d_in[3];
  const float* qkv_b_w  = (const float*)d_in[4];
  const float* qkv_w_s  = (const float*)d_in[5];
  const float* qkv_b_s  = (const float*)d_in[6];
  const float* proj_w   = (const float*)d_in[7];
  const float* proj_b   = (const float*)d_in[8];
  const float* rpb      = (const float*)d_in[9];
  const float* norm2_g  = (const float*)d_in[10];
  const float* norm2_b  = (const float*)d_in[11];
  const float* fc1_w    = (const float*)d_in[12];
  const float* fc1_b    = (const float*)d_in[13];
  const float* fc2_w    = (const float*)d_in[14];
  const float* fc2_b    = (const float*)d_in[15];
  const float* conv_w   = (const float*)d_in[16];
  const float* conv_b   = (const float*)d_in[17];

  char* ws = (char*)d_ws;
  float*  x_cur = (float*)ws;
  bf16_t* xn    = (bf16_t*)(ws + 56623104);
  bf16_t* qh    = (bf16_t*)(ws + 84934656);
  bf16_t* aoutb = (bf16_t*)(ws + 198180864);
  bf16_t* WwinT = (bf16_t*)(ws + 226492416);
  bf16_t* WstrT  = WwinT  + 110592;
  bf16_t* WprojT = WstrT  + 110592;
  bf16_t* Wfc1T  = WprojT + 147456;
  bf16_t* Wfc2T  = Wfc1T  + 589824;
  bf16_t* WconvT = Wfc2T  + 589824;
  float*  RPB2   = (float*)(WconvT + 331776);

  prep_all_k<<<7600, 256, 0, stream>>>(qkv_w_w, qkv_w_s, proj_w, fc1_w, fc2_w,
                                       conv_w, rpb,
                                       WwinT, WstrT, WprojT, Wfc1T, Wfc2T, WconvT, RPB2);

  ln0_k<<<TOKS/4, 256, 0, stream>>>(x_in, norm1_g, norm1_b, xn, x_cur);

  const int MB = TOKS/128;   // 576
  const int MQ = TOKS/256;   // 288
  for (int i = 0; i < 4; ++i) {
    int shift = (i % 2 == 0) ? 4 : 0;
    dim3 g6(MQ, 6), g4(MB, 4);
    gemmq_k<<<g6, 256, 0, stream>>>(xn, WwinT + (long)i*27648, WstrT + (long)i*27648,
                                    qkv_b_w + i*288, qkv_b_s + i*288, qh);
    attn_k<<<2304, 256, 0, stream>>>(qh, xn, aoutb, RPB2 + i*16384, shift);
    gemmb_k<0><<<MB, 512, 0, stream>>>(aoutb, WprojT + (long)i*36864, proj_b + i*192,
                                       x_cur, xn, norm2_g + i*192, norm2_b + i*192, 192);
    gemmf_k<<<g4, 512, 0, stream>>>(xn, Wfc1T + (long)i*147456, fc1_b + i*768, qh);
    if (i < 3)
      gemmb_k<0><<<MB, 512, 0, stream>>>(qh, Wfc2T + (long)i*147456, fc2_b + i*192,
                                         x_cur, xn, norm1_g + (i+1)*192, norm1_b + (i+1)*192, 768);
    else
      gemmb_k<1><<<MB, 512, 0, stream>>>(qh, Wfc2T + (long)i*147456, fc2_b + i*192,
                                         x_cur, aoutb, nullptr, nullptr, 768);
  }
  hipMemsetAsync(qh, 0, 4096, stream);
  dim3 gc(384, 3);
  conv6_k<<<gc, 256, 0, stream>>>(aoutb, WconvT, conv_b, x_in, qh, (float*)d_out);
}

// Round 15
// 908.185 us; speedup vs baseline: 1.1120x; 1.1120x over previous
//
#include <hip/hip_runtime.h>
#include <math.h>

typedef __bf16 bf16_t;
typedef bf16_t bf16x8 __attribute__((ext_vector_type(8)));
typedef bf16_t bf16x4 __attribute__((ext_vector_type(4)));
typedef float f32x4 __attribute__((ext_vector_type(4)));

#define TOKS 73728
#define CCH 192

__device__ __forceinline__ float gelu_f(float x) {
  float x2 = x*x;
  float u = 1.5957691216057308f * x * fmaf(0.044715f, x2, 1.0f);
  float e = __expf(-u);
  return x * __builtin_amdgcn_rcpf(1.0f + e);
}

__device__ __forceinline__ void glds16(const void* g, void* l) {
  __builtin_amdgcn_global_load_lds(
      (const __attribute__((address_space(1))) void*)g,
      (__attribute__((address_space(3))) void*)l, 16, 0, 0);
}

// ---------- fused prep ----------
__global__ void prep_all_k(const float* __restrict__ qw, const float* __restrict__ qs,
                           const float* __restrict__ pw, const float* __restrict__ f1,
                           const float* __restrict__ f2, const float* __restrict__ cw,
                           const float* __restrict__ rpb,
                           bf16_t* __restrict__ WwinT, bf16_t* __restrict__ WstrT,
                           bf16_t* __restrict__ WprojT, bf16_t* __restrict__ Wfc1T,
                           bf16_t* __restrict__ Wfc2T, bf16_t* __restrict__ WconvT,
                           float* __restrict__ RPB2) {
  long idx = (long)blockIdx.x*256 + threadIdx.x;
  auto tr = [](const float* in, bf16_t* out, long i, int K, int N) {
    long kn = (long)K*N;
    long c = i / kn;
    int rem = (int)(i - c*kn);
    int k = rem / N, n = rem % N;
    out[c*kn + (long)n*K + k] = (bf16_t)in[i];
  };
  if (idx < 110592)        tr(qw, WwinT, idx, 96, 288);
  else if (idx < 221184)   tr(qs, WstrT, idx-110592, 96, 288);
  else if (idx < 368640)   tr(pw, WprojT, idx-221184, 192, 192);
  else if (idx < 958464)   tr(f1, Wfc1T, idx-368640, 192, 768);
  else if (idx < 1548288)  tr(f2, Wfc2T, idx-958464, 768, 192);
  else if (idx < 1880064) {
    int i2 = (int)(idx - 1548288);
    int tap = i2 / 36864;
    int co = (i2 / 192) % 192;
    int ci = i2 % 192;
    WconvT[i2] = (bf16_t)cw[(co*192 + ci)*9 + tap];
  } else if (idx < 1945600) {
    int i2 = (int)(idx - 1880064);
    int i = i2 >> 14;
    int rem = i2 & 16383;
    int h = rem >> 12;
    int k = (rem >> 6) & 63;
    int c = (rem >> 2) & 15;
    int nt = rem & 3;
    int q = nt*16 + c;
    int ridx = ((q>>3) - (k>>3) + 7)*15 + ((q&7) - (k&7) + 7);
    RPB2[i2] = rpb[(i*225 + ridx)*4 + h];
  }
}

// ---------- LN0: x f32 -> xn bf16, and copy x -> x_cur (bf16) ----------
__global__ __launch_bounds__(256) void ln0_k(const float* __restrict__ x,
    const float* __restrict__ gg, const float* __restrict__ bb,
    bf16_t* __restrict__ out, bf16_t* __restrict__ xcopy) {
  const int wid = blockIdx.x*4 + (threadIdx.x >> 6);
  const int l = threadIdx.x & 63;
  const float* row = x + (long)wid*CCH;
  float v0 = row[l], v1 = row[l+64], v2 = row[l+128];
  float s = v0+v1+v2, s2 = v0*v0+v1*v1+v2*v2;
  #pragma unroll
  for (int off=1; off<64; off<<=1) { s += __shfl_xor(s, off); s2 += __shfl_xor(s2, off); }
  float mu = s * (1.f/CCH);
  float rstd = rsqrtf(s2*(1.f/CCH) - mu*mu + 1e-5f);
  bf16_t* crow = xcopy + (long)wid*CCH;
  crow[l] = (bf16_t)v0; crow[l+64] = (bf16_t)v1; crow[l+128] = (bf16_t)v2;
  bf16_t* orow = out + (long)wid*CCH;
  orow[l]     = (bf16_t)((v0-mu)*rstd*gg[l]     + bb[l]);
  orow[l+64]  = (bf16_t)((v1-mu)*rstd*gg[l+64]  + bb[l+64]);
  orow[l+128] = (bf16_t)((v2-mu)*rstd*gg[l+128] + bb[l+128]);
}

// ---------- fused qkv GEMM: win (y<3) + stripe (y>=3), K=96, BK=32 ----------
__global__ __launch_bounds__(256) void gemmq_k(
    const bf16_t* __restrict__ xn,
    const bf16_t* __restrict__ BtW, const bf16_t* __restrict__ BtS,
    const float* __restrict__ biasW, const float* __restrict__ biasS,
    bf16_t* __restrict__ outb) {
  constexpr int BK=32, MASK=3, RPS=16;
  __shared__ bf16_t As[2][128*32];
  __shared__ bf16_t Bs[2][96*32];
  const int tid = threadIdx.x;
  const int w = tid >> 6, l = tid & 63;
  const int lr = l & 15, lk = l >> 4;
  const int ri = l >> 2, si = l & MASK;
  const long m0 = (long)blockIdx.x * 128;
  const bool iswin = blockIdx.y < 3;
  const int n0 = (iswin ? blockIdx.y : blockIdx.y - 3) * 96;
  const bf16_t* A = iswin ? xn : xn + 96;
  const bf16_t* Bt = iswin ? BtW : BtS;
  const float* bias = iswin ? biasW : biasS;
  const int ooff = iswin ? 0 : 288;
  const int wm = w >> 1, wn = w & 1;

  f32x4 acc[4][3];
  #pragma unroll
  for (int mi=0;mi<4;++mi)
    #pragma unroll
    for (int ni=0;ni<3;++ni) acc[mi][ni] = (f32x4){0.f,0.f,0.f,0.f};

  auto stage = [&](int buf, int k0) {
    #pragma unroll
    for (int j = 0; j < 2; ++j) {
      const int s = j*4 + w;
      const int gr = s*RPS + ri;
      glds16(A + (m0+gr)*192L + k0 + ((si ^ (gr&MASK))*8), &As[buf][s*512]);
    }
    #pragma unroll
    for (int j = 0; j < 2; ++j) {
      const int s = j*4 + w;
      if (s < 6) {
        const int gr = s*RPS + ri;
        glds16(Bt + (long)(n0+gr)*96 + k0 + ((si ^ (gr&MASK))*8), &Bs[buf][s*512]);
      }
    }
  };

  stage(0, 0);
  __syncthreads();
  for (int kt = 0; kt < 3; ++kt) {
    const int cur = kt & 1;
    if (kt + 1 < 3) stage(cur^1, (kt+1)*BK);
    bf16x8 af[4], bfr[3];
    #pragma unroll
    for (int mi=0;mi<4;++mi) {
      const int ar = wm*64 + mi*16 + lr;
      const int slot = lk ^ (ar & MASK);
      af[mi] = *(const bf16x8*)(&As[cur][ar*32 + slot*8]);
    }
    #pragma unroll
    for (int ni=0;ni<3;++ni) {
      const int br = wn*48 + ni*16 + lr;
      const int slot = lk ^ (br & MASK);
      bfr[ni] = *(const bf16x8*)(&Bs[cur][br*32 + slot*8]);
    }
    #pragma unroll
    for (int mi=0;mi<4;++mi)
      #pragma unroll
      for (int ni=0;ni<3;++ni)
        acc[mi][ni] = __builtin_amdgcn_mfma_f32_16x16x32_bf16(af[mi], bfr[ni], acc[mi][ni], 0, 0, 0);
    __syncthreads();
  }

  #pragma unroll
  for (int mi=0;mi<4;++mi) {
    const long r0 = m0 + wm*64 + mi*16 + lk*4;
    #pragma unroll
    for (int ni=0;ni<3;++ni) {
      const int col = n0 + wn*48 + ni*16 + lr;
      const float bs = bias[col];
      #pragma unroll
      for (int e=0;e<4;++e) {
        const long row = r0 + e;
        outb[row*576 + ooff + col] = (bf16_t)(acc[mi][ni][e] + bs);
      }
    }
  }
}

// ---------- GEMM-B: BM=128, BN=192, BK=64, 512 threads, bf16 resid RMW (+LN) ----------
// EPI 0: resid RMW + LayerNorm -> xnout; EPI 1: read resid, write only xnout (final)
template<int EPI>
__global__ __launch_bounds__(512) void gemmb_k(
    const bf16_t* __restrict__ A,
    const bf16_t* __restrict__ Bt,
    const float* __restrict__ bias,
    bf16_t* __restrict__ resid,
    bf16_t* __restrict__ xnout,
    const float* __restrict__ gg, const float* __restrict__ bb,
    int K) {
  constexpr int BK=64, MASK=7;
  __shared__ bf16_t As[2][128*64];
  __shared__ bf16_t Bs[2][192*64];
  const int tid = threadIdx.x;
  const int w = tid >> 6, l = tid & 63;
  const int lr = l & 15, lk = l >> 4;
  const int ri = l >> 3, si = l & 7;
  const int wm = w >> 2, wn = w & 3;
  const long m0 = (long)blockIdx.x * 128;

  f32x4 acc[4][3];
  #pragma unroll
  for (int mi=0;mi<4;++mi)
    #pragma unroll
    for (int ni=0;ni<3;++ni) acc[mi][ni] = (f32x4){0.f,0.f,0.f,0.f};

  const int nk = K / BK;
  auto stage = [&](int buf, int k0) {
    #pragma unroll
    for (int j = 0; j < 2; ++j) {
      const int s = j*8 + w;
      const int gr = s*8 + ri;
      glds16(A + (m0+gr)*(long)K + k0 + ((si ^ (gr&MASK))*8), &As[buf][s*512]);
    }
    #pragma unroll
    for (int j = 0; j < 3; ++j) {
      const int s = j*8 + w;
      const int gr = s*8 + ri;
      glds16(Bt + (long)gr*K + k0 + ((si ^ (gr&MASK))*8), &Bs[buf][s*512]);
    }
  };

  stage(0, 0);
  __syncthreads();
  for (int kt = 0; kt < nk; ++kt) {
    const int cur = kt & 1;
    if (kt + 1 < nk) stage(cur^1, (kt+1)*BK);
    #pragma unroll
    for (int ks = 0; ks < 2; ++ks) {
      bf16x8 af[4], bfr[3];
      #pragma unroll
      for (int mi=0;mi<4;++mi) {
        const int ar = wm*64 + mi*16 + lr;
        const int slot = (ks*4 + lk) ^ (ar & MASK);
        af[mi] = *(const bf16x8*)(&As[cur][ar*64 + slot*8]);
      }
      #pragma unroll
      for (int ni=0;ni<3;++ni) {
        const int br = wn*48 + ni*16 + lr;
        const int slot = (ks*4 + lk) ^ (br & MASK);
        bfr[ni] = *(const bf16x8*)(&Bs[cur][br*64 + slot*8]);
      }
      #pragma unroll
      for (int mi=0;mi<4;++mi)
        #pragma unroll
        for (int ni=0;ni<3;++ni)
          acc[mi][ni] = __builtin_amdgcn_mfma_f32_16x16x32_bf16(af[mi], bfr[ni], acc[mi][ni], 0, 0, 0);
    }
    __syncthreads();
  }

  #pragma unroll
  for (int mi=0;mi<4;++mi) {
    #pragma unroll
    for (int ni=0;ni<3;++ni) {
      const int col = wn*48 + ni*16 + lr;
      const float bs = bias[col];
      #pragma unroll
      for (int e=0;e<4;++e) {
        const long row = m0 + wm*64 + mi*16 + lk*4 + e;
        float v = acc[mi][ni][e] + bs + (float)resid[row*CCH + col];
        acc[mi][ni][e] = v;
        if (EPI == 0) resid[row*CCH + col] = (bf16_t)v;
        else          xnout[row*CCH + col] = (bf16_t)v;
      }
    }
  }
  if (EPI == 0) {
    float* red  = (float*)&As[0][0];
    float* stat = red + 1024;
    #pragma unroll
    for (int mi=0;mi<4;++mi) {
      #pragma unroll
      for (int e=0;e<4;++e) {
        float p1 = acc[mi][0][e] + acc[mi][1][e] + acc[mi][2][e];
        float p2 = acc[mi][0][e]*acc[mi][0][e] + acc[mi][1][e]*acc[mi][1][e]
                 + acc[mi][2][e]*acc[mi][2][e];
        #pragma unroll
        for (int off=1; off<16; off<<=1) {
          p1 += __shfl_xor(p1, off);
          p2 += __shfl_xor(p2, off);
        }
        if (lr == 0) {
          const int r = wm*64 + mi*16 + lk*4 + e;
          red[(r*4 + wn)*2]     = p1;
          red[(r*4 + wn)*2 + 1] = p2;
        }
      }
    }
    __syncthreads();
    if (tid < 128) {
      const int r = tid;
      float s1 = red[(r*4+0)*2] + red[(r*4+1)*2] + red[(r*4+2)*2] + red[(r*4+3)*2];
      float s2 = red[(r*4+0)*2+1] + red[(r*4+1)*2+1] + red[(r*4+2)*2+1] + red[(r*4+3)*2+1];
      const float mu = s1 * (1.f/CCH);
      stat[r*2]   = mu;
      stat[r*2+1] = rsqrtf(s2*(1.f/CCH) - mu*mu + 1e-5f);
    }
    __syncthreads();
    #pragma unroll
    for (int mi=0;mi<4;++mi) {
      #pragma unroll
      for (int e=0;e<4;++e) {
        const int r = wm*64 + mi*16 + lk*4 + e;
        const float mu = stat[r*2], rstd = stat[r*2+1];
        #pragma unroll
        for (int ni=0;ni<3;++ni) {
          const int col = wn*48 + ni*16 + lr;
          xnout[(m0+r)*CCH + col] = (bf16_t)((acc[mi][ni][e]-mu)*rstd*gg[col] + bb[col]);
        }
      }
    }
  }
}

// ---------- fc1 GEMM: BM=128, BN=192 (of N=768), BK=64, 512 thr, gelu ----------
__global__ __launch_bounds__(512) void gemmf_k(
    const bf16_t* __restrict__ A,
    const bf16_t* __restrict__ Bt,
    const float* __restrict__ bias,
    bf16_t* __restrict__ outb) {
  constexpr int BK=64, MASK=7;
  __shared__ bf16_t As[2][128*64];
  __shared__ bf16_t Bs[2][192*64];
  const int tid = threadIdx.x;
  const int w = tid >> 6, l = tid & 63;
  const int lr = l & 15, lk = l >> 4;
  const int ri = l >> 3, si = l & 7;
  const int wm = w >> 2, wn = w & 3;
  const long m0 = (long)blockIdx.x * 128;
  const int n0 = blockIdx.y * 192;

  f32x4 acc[4][3];
  #pragma unroll
  for (int mi=0;mi<4;++mi)
    #pragma unroll
    for (int ni=0;ni<3;++ni) acc[mi][ni] = (f32x4){0.f,0.f,0.f,0.f};

  auto stage = [&](int buf, int k0) {
    #pragma unroll
    for (int j = 0; j < 2; ++j) {
      const int s = j*8 + w;
      const int gr = s*8 + ri;
      glds16(A + (m0+gr)*192L + k0 + ((si ^ (gr&MASK))*8), &As[buf][s*512]);
    }
    #pragma unroll
    for (int j = 0; j < 3; ++j) {
      const int s = j*8 + w;
      const int gr = s*8 + ri;
      glds16(Bt + (long)(n0+gr)*192 + k0 + ((si ^ (gr&MASK))*8), &Bs[buf][s*512]);
    }
  };

  stage(0, 0);
  __syncthreads();
  for (int kt = 0; kt < 3; ++kt) {
    const int cur = kt & 1;
    if (kt + 1 < 3) stage(cur^1, (kt+1)*BK);
    #pragma unroll
    for (int ks = 0; ks < 2; ++ks) {
      bf16x8 af[4], bfr[3];
      #pragma unroll
      for (int mi=0;mi<4;++mi) {
        const int ar = wm*64 + mi*16 + lr;
        const int slot = (ks*4 + lk) ^ (ar & MASK);
        af[mi] = *(const bf16x8*)(&As[cur][ar*64 + slot*8]);
      }
      #pragma unroll
      for (int ni=0;ni<3;++ni) {
        const int br = wn*48 + ni*16 + lr;
        const int slot = (ks*4 + lk) ^ (br & MASK);
        bfr[ni] = *(const bf16x8*)(&Bs[cur][br*64 + slot*8]);
      }
      #pragma unroll
      for (int mi=0;mi<4;++mi)
        #pragma unroll
        for (int ni=0;ni<3;++ni)
          acc[mi][ni] = __builtin_amdgcn_mfma_f32_16x16x32_bf16(af[mi], bfr[ni], acc[mi][ni], 0, 0, 0);
    }
    __syncthreads();
  }

  #pragma unroll
  for (int mi=0;mi<4;++mi) {
    #pragma unroll
    for (int ni=0;ni<3;++ni) {
      const int col = n0 + wn*48 + ni*16 + lr;
      const float bs = bias[col];
      #pragma unroll
      for (int e=0;e<4;++e) {
        const long row = m0 + wm*64 + mi*16 + lk*4 + e;
        outb[row*768 + col] = (bf16_t)gelu_f(acc[mi][ni][e] + bs);
      }
    }
  }
}

// ---------- fused attention: blocks <1152 window (MFMA), >=1152 stripe (MFMA) ----------
__global__ __launch_bounds__(256) void attn_k(
    const bf16_t* __restrict__ qkv, const bf16_t* __restrict__ xn,
    bf16_t* __restrict__ aout,
    const float* __restrict__ rpb2, int shift) {
  __shared__ __attribute__((aligned(16))) char smem[50176];
  const int h = threadIdx.x >> 6, l = threadIdx.x & 63;
  const int c = l & 15, g = l >> 4;
  const float scale = 0.20412414523193154f;

  if (blockIdx.x < 1152) {
    bf16_t (*Vs)[64][28] = (bf16_t(*)[64][28])smem;
    bf16_t (*Pl)[64][68] = (bf16_t(*)[64][68])(smem + 14336);
    float  (*invl)[64]   = (float(*)[64])(smem + 49152);
    const int wblk = blockIdx.x;
    const int b = wblk / 576, wi = wblk % 576;
    const int wh = wi / 24, ww = wi % 24;

    auto gtok = [&](int t) -> long {
      int ho = wh*8 + (t>>3) + shift; if (ho >= 192) ho -= 192;
      int wo = ww*8 + (t&7) + shift;  if (wo >= 192) wo -= 192;
      return (long)b*36864 + (long)ho*192 + wo;
    };

    {
      const bf16_t* vsrc = qkv + gtok(l)*576 + 192 + h*24;
      #pragma unroll
      for (int j=0;j<3;++j) {
        *(bf16x4*)(&Vs[h][l][j*8])   = *(const bf16x4*)(vsrc + j*8);
        *(bf16x4*)(&Vs[h][l][j*8+4]) = *(const bf16x4*)(vsrc + j*8 + 4);
      }
      *(bf16x4*)(&Vs[h][l][24]) = (bf16x4){};
    }

    bf16x8 kf[4], qf[4];
    #pragma unroll
    for (int t=0;t<4;++t) {
      bf16x8 z = {};
      kf[t] = z; qf[t] = z;
      if (g < 3) {
        const bf16_t* pb = qkv + gtok(16*t + c)*576 + h*24 + g*8;
        qf[t] = *(const bf16x8*)(pb);
        kf[t] = *(const bf16x8*)(pb + 96);
      }
    }

    f32x4 st[4][4];
    #pragma unroll
    for (int mt=0;mt<4;++mt)
      #pragma unroll
      for (int nt=0;nt<4;++nt)
        st[mt][nt] = __builtin_amdgcn_mfma_f32_16x16x32_bf16(kf[mt], qf[nt], (f32x4){0.f,0.f,0.f,0.f}, 0, 0, 0);

    const float4* rp = (const float4*)rpb2 + (h*64*16 + c);
    #pragma unroll
    for (int mt=0;mt<4;++mt) {
      #pragma unroll
      for (int r=0;r<4;++r) {
        const int k = 16*mt + 4*g + r;
        float4 b4 = rp[k*16];
        st[mt][0][r] = fmaf(st[mt][0][r], scale, b4.x);
        st[mt][1][r] = fmaf(st[mt][1][r], scale, b4.y);
        st[mt][2][r] = fmaf(st[mt][2][r], scale, b4.z);
        st[mt][3][r] = fmaf(st[mt][3][r], scale, b4.w);
      }
    }

    if (shift && (wh==23 || ww==23)) {
      #pragma unroll
      for (int mt=0;mt<4;++mt)
        #pragma unroll
        for (int r=0;r<4;++r) {
          const int kk = 16*mt + 4*g + r;
          const int krc = (wh==23) ? (((kk>>3)<4)?1:2) : 0;
          const int kcc = (ww==23) ? (((kk&7)<4)?1:2) : 0;
          const int kcls = krc*3 + kcc;
          #pragma unroll
          for (int nt=0;nt<4;++nt) {
            const int qq = 16*nt + c;
            const int qrc = (wh==23) ? (((qq>>3)<4)?1:2) : 0;
            const int qcc = (ww==23) ? (((qq&7)<4)?1:2) : 0;
            if (qrc*3 + qcc != kcls) st[mt][nt][r] -= 100.f;
          }
        }
    }

    #pragma unroll
    for (int nt=0;nt<4;++nt) {
      float m = st[0][nt][0];
      #pragma unroll
      for (int mt=0;mt<4;++mt)
        #pragma unroll
        for (int r=0;r<4;++r) m = fmaxf(m, st[mt][nt][r]);
      m = fmaxf(m, __shfl_xor(m, 16));
      m = fmaxf(m, __shfl_xor(m, 32));
      float s = 0.f;
      #pragma unroll
      for (int mt=0;mt<4;++mt)
        #pragma unroll
        for (int r=0;r<4;++r) {
          float p = __expf(st[mt][nt][r] - m);
          st[mt][nt][r] = p;
          s += p;
        }
      s += __shfl_xor(s, 16);
      s += __shfl_xor(s, 32);
      if (g == 0) invl[h][16*nt + c] = 1.f / s;
    }

    #pragma unroll
    for (int mt=0;mt<4;++mt) {
      #pragma unroll
      for (int nt=0;nt<4;++nt) {
        const int q = 16*nt + c;
        const int sl = (4*mt + g) ^ ((q&7)<<1);
        bf16x4 pk;
        #pragma unroll
        for (int r=0;r<4;++r) pk[r] = (bf16_t)st[mt][nt][r];
        *(bf16x4*)(&Pl[h][q][sl*4]) = pk;
      }
    }

    f32x4 oa[4][2];
    #pragma unroll
    for (int mt=0;mt<4;++mt)
      #pragma unroll
      for (int nt=0;nt<2;++nt) oa[mt][nt] = (f32x4){0.f,0.f,0.f,0.f};

    #pragma unroll
    for (int s2=0;s2<2;++s2) {
      bf16x8 pfr[4];
      #pragma unroll
      for (int mt=0;mt<4;++mt) {
        const int q = 16*mt + c;
        const int S0 = (8*s2 + 2*g) ^ ((q&7)<<1);
        bf16x4 lo = *(const bf16x4*)(&Pl[h][q][S0*4]);
        bf16x4 hi = *(const bf16x4*)(&Pl[h][q][S0*4 + 4]);
        #pragma unroll
        for (int r=0;r<4;++r) { pfr[mt][r] = lo[r]; pfr[mt][4+r] = hi[r]; }
      }
      #pragma unroll
      for (int nt=0;nt<2;++nt) {
        const int d = 16*nt + c;
        const int deff = (d < 24) ? d : 24;
        bf16x8 vf;
        #pragma unroll
        for (int e=0;e<8;++e) vf[e] = Vs[h][32*s2 + 8*g + e][deff];
        #pragma unroll
        for (int mt=0;mt<4;++mt)
          oa[mt][nt] = __builtin_amdgcn_mfma_f32_16x16x32_bf16(pfr[mt], vf, oa[mt][nt], 0, 0, 0);
      }
    }

    #pragma unroll
    for (int mt=0;mt<4;++mt) {
      #pragma unroll
      for (int r=0;r<4;++r) {
        const int q = 16*mt + 4*g + r;
        const float inv = invl[h][q];
        bf16_t* ob = aout + gtok(q)*192 + h*24;
        #pragma unroll
        for (int nt=0;nt<2;++nt) {
          const int d = 16*nt + c;
          if (d < 24) ob[d] = (bf16_t)(oa[mt][nt][r] * inv);
        }
      }
    }
  } else {
    bf16_t (*Vs)[64][28]  = (bf16_t(*)[64][28])smem;
    bf16_t (*Ans)[16][40] = (bf16_t(*)[16][40])(smem + 14336);
    bf16_t (*a2s)[16][68] = (bf16_t(*)[16][68])(smem + 19456);
    bf16_t (*a1s)[64][24] = (bf16_t(*)[64][24])(smem + 28160);
    bf16_t (*Ts2)[32][28] = (bf16_t(*)[32][28])(smem + 40448);
    const int wblk = blockIdx.x - 1152;
    const int b = wblk / 576, wi = wblk % 576;
    const int wh = wi / 24, ww = wi % 24;
    const long base0 = (long)b*36864 + (long)(wh*8)*192 + ww*8;
    auto gtok = [&](int t) -> long { return base0 + (long)(t>>3)*192 + (t&7); };

    {
      const bf16_t* vsrc = qkv + gtok(l)*576 + 480 + h*24;
      #pragma unroll
      for (int j=0;j<3;++j) {
        *(bf16x4*)(&Vs[h][l][j*8])   = *(const bf16x4*)(vsrc + j*8);
        *(bf16x4*)(&Vs[h][l][j*8+4]) = *(const bf16x4*)(vsrc + j*8 + 4);
      }
      *(bf16x4*)(&Vs[h][l][24]) = (bf16x4){};
    }
    {
      const int m = l >> 2, dq = l & 3;
      const int ar = m >> 2, ac = m & 3;
      const bf16_t* t0 = xn + (base0 + (long)(2*ar)*192 + 2*ac)*192 + 96 + h*24;
      #pragma unroll
      for (int j=0;j<6;++j) {
        const int d = dq*6 + j;
        float ssum = (float)t0[d] + (float)t0[192+d] + (float)t0[36864+d] + (float)t0[37056+d];
        Ans[h][m][d] = (bf16_t)(0.25f*ssum);
      }
    }
    if (l < 16) {
      *(bf16x4*)(&Ans[h][l][24]) = (bf16x4){};
      *(bf16x4*)(&Ans[h][l][28]) = (bf16x4){};
      bf16_t* z = &Ts2[h][16+l][0];
      #pragma unroll
      for (int j=0;j<7;++j) *(bf16x4*)(z + j*4) = (bf16x4){};
      *(bf16x4*)(&Ts2[h][l][24]) = (bf16x4){};
    }

    bf16x8 anf = *(const bf16x8*)(&Ans[h][c][g*8]);

    bf16x8 kf[4], qf[4];
    #pragma unroll
    for (int t=0;t<4;++t) {
      const bf16_t* pb = qkv + gtok(16*t + c)*576 + 288 + h*24 + g*8;
      qf[t] = *(const bf16x8*)(pb);
      kf[t] = *(const bf16x8*)(pb + 96);
    }

    f32x4 st2[4];
    #pragma unroll
    for (int mt=0;mt<4;++mt)
      st2[mt] = __builtin_amdgcn_mfma_f32_16x16x32_bf16(kf[mt], anf, (f32x4){0.f,0.f,0.f,0.f}, 0, 0, 0);

    {
      float m2 = -1e30f;
      #pragma unroll
      for (int mt=0;mt<4;++mt)
        #pragma unroll
        for (int r=0;r<4;++r) { st2[mt][r] *= scale; m2 = fmaxf(m2, st2[mt][r]); }
      m2 = fmaxf(m2, __shfl_xor(m2, 16));
      m2 = fmaxf(m2, __shfl_xor(m2, 32));
      float s = 0.f;
      #pragma unroll
      for (int mt=0;mt<4;++mt)
        #pragma unroll
        for (int r=0;r<4;++r) { float p = __expf(st2[mt][r] - m2); st2[mt][r] = p; s += p; }
      s += __shfl_xor(s, 16);
      s += __shfl_xor(s, 32);
      const float inv = 1.f / s;
      #pragma unroll
      for (int mt=0;mt<4;++mt) {
        const int sl = (4*mt + g) ^ ((c&7)<<1);
        bf16x4 pk;
        #pragma unroll
        for (int r=0;r<4;++r) pk[r] = (bf16_t)(st2[mt][r] * inv);
        *(bf16x4*)(&a2s[h][c][sl*4]) = pk;
      }
    }

    f32x4 ta[2];
    ta[0] = (f32x4){0.f,0.f,0.f,0.f}; ta[1] = (f32x4){0.f,0.f,0.f,0.f};
    #pragma unroll
    for (int kt=0;kt<2;++kt) {
      const int S0 = (8*kt + 2*g) ^ ((c&7)<<1);
      bf16x4 lo = *(const bf16x4*)(&a2s[h][c][S0*4]);
      bf16x4 hi = *(const bf16x4*)(&a2s[h][c][S0*4 + 4]);
      bf16x8 pf;
      #pragma unroll
      for (int r=0;r<4;++r) { pf[r] = lo[r]; pf[4+r] = hi[r]; }
      #pragma unroll
      for (int nt2=0;nt2<2;++nt2) {
        const int d = 16*nt2 + c;
        const int deff = (d < 24) ? d : 24;
        bf16x8 vf;
        #pragma unroll
        for (int e=0;e<8;++e) vf[e] = Vs[h][kt*32 + 8*g + e][deff];
        ta[nt2] = __builtin_amdgcn_mfma_f32_16x16x32_bf16(pf, vf, ta[nt2], 0, 0, 0);
      }
    }
    #pragma unroll
    for (int nt2=0;nt2<2;++nt2) {
      const int d = 16*nt2 + c;
      if (d < 24) {
        #pragma unroll
        for (int r=0;r<4;++r) Ts2[h][4*g + r][d] = (bf16_t)ta[nt2][r];
      }
    }

    f32x4 st1[4];
    #pragma unroll
    for (int nt=0;nt<4;++nt)
      st1[nt] = __builtin_amdgcn_mfma_f32_16x16x32_bf16(anf, qf[nt], (f32x4){0.f,0.f,0.f,0.f}, 0, 0, 0);

    #pragma unroll
    for (int nt=0;nt<4;++nt) {
      float m1 = -1e30f;
      #pragma unroll
      for (int r=0;r<4;++r) { st1[nt][r] *= scale; m1 = fmaxf(m1, st1[nt][r]); }
      m1 = fmaxf(m1, __shfl_xor(m1, 16));
      m1 = fmaxf(m1, __shfl_xor(m1, 32));
      float s = 0.f;
      #pragma unroll
      for (int r=0;r<4;++r) { float p = __expf(st1[nt][r] - m1); st1[nt][r] = p; s += p; }
      s += __shfl_xor(s, 16);
      s += __shfl_xor(s, 32);
      const float inv1 = 1.f / s;
      bf16x4 ak;
      #pragma unroll
      for (int r=0;r<4;++r) ak[r] = (bf16_t)(st1[nt][r] * inv1);
      *(bf16x4*)(&a1s[h][16*nt + c][4*g]) = ak;
    }

    f32x4 oa[4][2];
    #pragma unroll
    for (int mt=0;mt<4;++mt) { oa[mt][0] = (f32x4){0.f,0.f,0.f,0.f}; oa[mt][1] = (f32x4){0.f,0.f,0.f,0.f}; }
    #pragma unroll
    for (int mt=0;mt<4;++mt) {
      bf16x8 af = {};
      if (g < 2) af = *(const bf16x8*)(&a1s[h][16*mt + c][g*8]);
      #pragma unroll
      for (int nt2=0;nt2<2;++nt2) {
        const int d = 16*nt2 + c;
        const int deff = (d < 24) ? d : 24;
        bf16x8 tf;
        #pragma unroll
        for (int e=0;e<8;++e) tf[e] = Ts2[h][8*g + e][deff];
        oa[mt][nt2] = __builtin_amdgcn_mfma_f32_16x16x32_bf16(af, tf, oa[mt][nt2], 0, 0, 0);
      }
    }

    #pragma unroll
    for (int mt=0;mt<4;++mt) {
      #pragma unroll
      for (int r=0;r<4;++r) {
        const int tw = 16*mt + 4*g + r;
        bf16_t* ob = aout + gtok(tw)*192 + 96 + h*24;
        #pragma unroll
        for (int nt2=0;nt2<2;++nt2) {
          const int d = 16*nt2 + c;
          if (d < 24) ob[d] = (bf16_t)(oa[mt][nt2][r]);
        }
      }
    }
  }
}

// ---------- conv v5: 52KB LDS (3 blocks/CU), tap-row weight staging ----------
__global__ __launch_bounds__(256) void conv5_k(
    const bf16_t* __restrict__ xb,
    const bf16_t* __restrict__ Wc,
    const float* __restrict__ cb,
    const float* __restrict__ res0,
    const bf16_t* __restrict__ zb,
    float* __restrict__ out) {
  __shared__ bf16_t Xs[19968];
  __shared__ bf16_t Bs[6144];
  const int tid = threadIdx.x;
  const int w = tid >> 6, l = tid & 63;
  const int lr = l & 15, lk = l >> 4;
  const int rq = l >> 2, cq = (l & 3) * 8;
  const int bxr = blockIdx.x;
  const int bx = (bxr & 7) * 48 + (bxr >> 3);
  const int bimg = bx / 192, h = bx % 192;
  const int co0 = blockIdx.y * 64;

  f32x4 acc[3][4];
  #pragma unroll
  for (int mi=0; mi<3; ++mi)
    #pragma unroll
    for (int ni=0; ni<4; ++ni) acc[mi][ni] = (f32x4){0.f,0.f,0.f,0.f};

  auto stageB = [&](int dyg, int kc) {
    #pragma unroll
    for (int j = 0; j < 3; ++j) {
      const int s = j*4 + w;
      const int tap = s >> 2, rem = s & 3;
      const int row = rem*16 + rq;
      glds16(Wc + ((long)((dyg*3 + tap)*192 + co0 + row))*192 + kc + cq, &Bs[s*512]);
    }
  };
  auto compute = [&](int dyg) {
    #pragma unroll
    for (int tap = 0; tap < 3; ++tap) {
      bf16x8 af[3];
      #pragma unroll
      for (int mi=0; mi<3; ++mi) {
        const int tokcol = w*48 + mi*16 + lr + tap;
        af[mi] = *(const bf16x8*)(&Xs[dyg*6656 + tokcol*32 + lk*8]);
      }
      #pragma unroll
      for (int ni=0; ni<4; ++ni) {
        bf16x8 bfr = *(const bf16x8*)(&Bs[tap*2048 + (ni*16+lr)*32 + lk*8]);
        #pragma unroll
        for (int mi=0; mi<3; ++mi)
          acc[mi][ni] = __builtin_amdgcn_mfma_f32_16x16x32_bf16(af[mi], bfr, acc[mi][ni], 0, 0, 0);
      }
    }
  };

  for (int kcs = 0; kcs < 6; ++kcs) {
    const int kc = kcs * 32;
    if (kcs) __syncthreads();
    for (int j = 0; j < 10; ++j) {
      int s = j*4 + w;
      if (s < 39) {
        int dy = s / 13, rem = s - dy*13;
        int tokcol = rem*16 + rq;
        int wc = tokcol - 1;
        int hp = h + dy - 1;
        const bf16_t* src = zb + cq;
        if (hp >= 0 && hp < 192 && wc >= 0 && wc < 192)
          src = xb + ((long)bimg*36864 + (long)hp*192 + wc)*192 + kc + cq;
        glds16(src, &Xs[s*512]);
      }
    }
    stageB(0, kc);
    __syncthreads();
    compute(0);
    #pragma unroll
    for (int dyg = 1; dyg < 3; ++dyg) {
      __syncthreads();
      stageB(dyg, kc);
      __syncthreads();
      compute(dyg);
    }
  }

  #pragma unroll
  for (int mi=0; mi<3; ++mi) {
    #pragma unroll
    for (int ni=0; ni<4; ++ni) {
      const int col = co0 + ni*16 + lr;
      const float cbv = cb[col];
      #pragma unroll
      for (int e=0; e<4; ++e) {
        const int tl = w*48 + mi*16 + lk*4 + e;
        const long tok = (long)bimg*36864 + (long)h*192 + tl;
        out[tok*192 + col] = acc[mi][ni][e] + cbv + res0[tok*192 + col];
      }
    }
  }
}

extern "C" void kernel_launch(void* const* d_in, const int* in_sizes, int n_in,
                              void* d_out, int out_size, void* d_ws, size_t ws_size,
                              hipStream_t stream) {
  const float* x_in     = (const float*)d_in[0];
  const float* norm1_g  = (const float*)d_in[1];
  const float* norm1_b  = (const float*)d_in[2];
  const float* qkv_w_w  = (const float*)d_in[3];
  const float* qkv_b_w  = (const float*)d_in[4];
  const float* qkv_w_s  = (const float*)d_in[5];
  const float* qkv_b_s  = (const float*)d_in[6];
  const float* proj_w   = (const float*)d_in[7];
  const float* proj_b   = (const float*)d_in[8];
  const float* rpb      = (const float*)d_in[9];
  const float* norm2_g  = (const float*)d_in[10];
  const float* norm2_b  = (const float*)d_in[11];
  const float* fc1_w    = (const float*)d_in[12];
  const float* fc1_b    = (const float*)d_in[13];
  const float* fc2_w    = (const float*)d_in[14];
  const float* fc2_b    = (const float*)d_in[15];
  const float* conv_w   = (const float*)d_in[16];
  const float* conv_b   = (const float*)d_in[17];

  char* ws = (char*)d_ws;
  bf16_t* x_cur = (bf16_t*)ws;                        // 28,311,552 B (bf16 resid)
  bf16_t* xn    = (bf16_t*)(ws + 56623104);
  bf16_t* qh    = (bf16_t*)(ws + 84934656);
  bf16_t* aoutb = (bf16_t*)(ws + 198180864);
  bf16_t* WwinT = (bf16_t*)(ws + 226492416);
  bf16_t* WstrT  = WwinT  + 110592;
  bf16_t* WprojT = WstrT  + 110592;
  bf16_t* Wfc1T  = WprojT + 147456;
  bf16_t* Wfc2T  = Wfc1T  + 589824;
  bf16_t* WconvT = Wfc2T  + 589824;
  float*  RPB2   = (float*)(WconvT + 331776);

  prep_all_k<<<7600, 256, 0, stream>>>(qkv_w_w, qkv_w_s, proj_w, fc1_w, fc2_w,
                                       conv_w, rpb,
                                       WwinT, WstrT, WprojT, Wfc1T, Wfc2T, WconvT, RPB2);

  ln0_k<<<TOKS/4, 256, 0, stream>>>(x_in, norm1_g, norm1_b, xn, x_cur);

  const int MB = TOKS/128;   // 576
  for (int i = 0; i < 4; ++i) {
    int shift = (i % 2 == 0) ? 4 : 0;
    dim3 g6(MB, 6), g4(MB, 4);
    gemmq_k<<<g6, 256, 0, stream>>>(xn, WwinT + (long)i*27648, WstrT + (long)i*27648,
                                    qkv_b_w + i*288, qkv_b_s + i*288, qh);
    attn_k<<<2304, 256, 0, stream>>>(qh, xn, aoutb, RPB2 + i*16384, shift);
    gemmb_k<0><<<MB, 512, 0, stream>>>(aoutb, WprojT + (long)i*36864, proj_b + i*192,
                                       x_cur, xn, norm2_g + i*192, norm2_b + i*192, 192);
    gemmf_k<<<g4, 512, 0, stream>>>(xn, Wfc1T + (long)i*147456, fc1_b + i*768, qh);
    if (i < 3)
      gemmb_k<0><<<MB, 512, 0, stream>>>(qh, Wfc2T + (long)i*147456, fc2_b + i*192,
                                         x_cur, xn, norm1_g + (i+1)*192, norm1_b + (i+1)*192, 768);
    else
      gemmb_k<1><<<MB, 512, 0, stream>>>(qh, Wfc2T + (long)i*147456, fc2_b + i*192,
                                         x_cur, aoutb, nullptr, nullptr, 768);
  }
  hipMemsetAsync(qh, 0, 4096, stream);
  dim3 gc(384, 3);
  conv5_k<<<gc, 256, 0, stream>>>(aoutb, WconvT, conv_b, x_in, qh, (float*)d_out);
}